// Round 1
// baseline (373.528 us; speedup 1.0000x reference)
//
#include <hip/hip_runtime.h>

typedef unsigned short ushort_t;
typedef unsigned int uint_t;

// ---------------------------------------------------------------------------
// GCN 3-layer forward.  N=50000, E=800000, D=H=128, C=40.
// Round 18: fuse agg(L)+gemm(L+1) into single-block kernels.  gemm of tile
// [bm,bm+64) only needs agg output of those same 64 rows, so each block
// aggregates its rows into LDS (fp32, +bias, ReLU — identical numerics to
// the old bufB path) then GEMMs from LDS.  Kills the 102 MB bufB fp32
// round-trip and 2 dispatches; 3 blocks/CU (49.7 KB LDS) lets gather-phase
// blocks overlap GEMM-phase blocks on the same CU (m114 co-scheduling).
// Chain: memset -> k_l1(gemm1 ∪ deg) -> scan -> fill -> ag128(agg1+gemm2)
//        -> ag40(agg2+gemm3) -> agg40.
// ws layout: [deg:N int][partials:nb u64][rowptr:N+1][cursor:N][dinv:N f32]
//            [csr:E int2][bufA:N*128 bf16][bufC:N*128 bf16][bufD:N*64 bf16]
// ---------------------------------------------------------------------------

// Single-dispatch scan, wave-parallel decoupled lookback (R16).
__global__ __launch_bounds__(256) void k_scan(
        const int* __restrict__ deg, unsigned long long* __restrict__ partials,
        int* __restrict__ rowptr, int* __restrict__ cursor,
        float* __restrict__ dinv, int n) {
    __shared__ int s[256];
    __shared__ int sprefix;
    const int b = blockIdx.x, t = threadIdx.x;
    const int i = b * 256 + t;
    int v = (i < n) ? deg[i] : 0;
    s[t] = v;
    __syncthreads();
    for (int off = 1; off < 256; off <<= 1) {
        int u = (t >= off) ? s[t - off] : 0;
        __syncthreads();
        s[t] += u;
        __syncthreads();
    }
    if (t == 0) {
        __hip_atomic_store(&partials[b],
                ((unsigned long long)s[255] << 2) | 1ull,
                __ATOMIC_RELEASE, __HIP_MEMORY_SCOPE_AGENT);
        if (b == 0) {
            __hip_atomic_store(&partials[0],
                    ((unsigned long long)s[255] << 2) | 2ull,
                    __ATOMIC_RELEASE, __HIP_MEMORY_SCOPE_AGENT);
            sprefix = 0;
        }
    }
    if (b > 0 && t < 64) {
        int acc = 0;
        int k = b - 1;
        for (;;) {
            int idx = k - t;
            unsigned long long p;
            unsigned st;
            do {
                if (idx >= 0) {
                    p = __hip_atomic_load(&partials[idx],
                            __ATOMIC_ACQUIRE, __HIP_MEMORY_SCOPE_AGENT);
                } else {
                    p = 2ull;
                }
                st = (unsigned)(p & 3ull);
            } while (st == 0);
            unsigned long long bal = __ballot(st == 2);
            int L = (bal != 0) ? (__ffsll((unsigned long long)bal) - 1) : 64;
            int val = (int)(p >> 2);
            int contrib = (t <= L) ? val : 0;
            #pragma unroll
            for (int o = 32; o > 0; o >>= 1) contrib += __shfl_down(contrib, o);
            if (t == 0) acc += contrib;
            if (L < 64) break;
            k -= 64;
        }
        if (t == 0) {
            __hip_atomic_store(&partials[b],
                    (((unsigned long long)(acc + s[255])) << 2) | 2ull,
                    __ATOMIC_RELEASE, __HIP_MEMORY_SCOPE_AGENT);
            sprefix = acc;
        }
    }
    __syncthreads();
    if (i < n) {
        int ex = sprefix + s[t] - v;
        rowptr[i] = ex;
        cursor[i] = ex;
        dinv[i] = rsqrtf((float)(v + 1));
        if (i == n - 1) rowptr[n] = ex + v;
    }
}

// XCD-partitioned scatter (R12).
__global__ __launch_bounds__(256) void k_fill(const int* __restrict__ ei,
                                              int* __restrict__ cursor,
                                              const float* __restrict__ dinv,
                                              int2* __restrict__ csr, int E, int n) {
    const int xcd = blockIdx.x & 7;
    const int e = (blockIdx.x >> 3) * 256 + threadIdx.x;
    if (e >= E) return;
    int d = ei[E + e];
    const int lo = (int)(((long long)xcd * n) >> 3);
    const int hi = (int)(((long long)(xcd + 1) * n) >> 3);
    if (d < lo || d >= hi) return;
    int s = ei[e];
    int pos = atomicAdd(&cursor[d], 1);
    int2 p;
    p.x = s;
    p.y = __float_as_int(dinv[s] * dinv[d]);
    csr[pos] = p;
}

__device__ __forceinline__ ushort_t f2bf_rne(float f) {
    uint_t u = __float_as_uint(f);
    u += 0x7fffu + ((u >> 16) & 1u);
    return (ushort_t)(u >> 16);
}
__device__ __forceinline__ float bflo(uint_t u) {
    return __uint_as_float(u << 16);
}
__device__ __forceinline__ float bfhi(uint_t u) {
    return __uint_as_float(u & 0xffff0000u);
}

// ---- UNION: blocks [0,gemmGrid) = Ybf16[N,128]=X@W1 (BM=128, 8x8 utile);
//      blocks [gemmGrid, ...) = deg_count (1 edge/thread).  Independent work.
__global__ __launch_bounds__(256) void k_l1(const float* __restrict__ X,
                                            const float* __restrict__ W,
                                            ushort_t* __restrict__ Y, int N,
                                            const int* __restrict__ ei,
                                            int* __restrict__ deg, int E,
                                            int gemmGrid) {
    __shared__ float sX[32][132];
    __shared__ float sW[32][128];
    if ((int)blockIdx.x >= gemmGrid) {
        int e = ((int)blockIdx.x - gemmGrid) * 256 + threadIdx.x;
        if (e < E) atomicAdd(&deg[ei[E + e]], 1);   // dst = ei[E+e]
        return;
    }
    const int tid = threadIdx.x;
    const int bm = blockIdx.x * 128;
    const int m0 = (tid >> 4) * 8;
    const int c4 = (tid & 15) * 4;
    const int xf = tid & 7;
    float acc[8][8] = {};
    for (int k0 = 0; k0 < 128; k0 += 32) {
        #pragma unroll
        for (int it = 0; it < 4; ++it) {
            int i = tid + it * 256;
            int row = bm + (i >> 3);
            int rc = min(row, N - 1);
            float4 v = *(const float4*)(X + (size_t)rc * 128 + k0 + xf * 4);
            int m = i >> 3;
            sX[xf * 4 + 0][m] = v.x;
            sX[xf * 4 + 1][m] = v.y;
            sX[xf * 4 + 2][m] = v.z;
            sX[xf * 4 + 3][m] = v.w;
        }
        #pragma unroll
        for (int it = 0; it < 4; ++it) {
            int i = tid + it * 256;
            int wr = i >> 5;
            int wf = i & 31;
            *(float4*)(&sW[wr][wf * 4]) =
                *(const float4*)(W + (size_t)(k0 + wr) * 128 + wf * 4);
        }
        __syncthreads();
        #pragma unroll
        for (int kk = 0; kk < 32; ++kk) {
            float4 a0 = *(const float4*)(&sX[kk][m0]);
            float4 a1 = *(const float4*)(&sX[kk][m0 + 4]);
            float4 b0 = *(const float4*)(&sW[kk][c4]);
            float4 b1 = *(const float4*)(&sW[kk][64 + c4]);
            float av[8] = {a0.x, a0.y, a0.z, a0.w, a1.x, a1.y, a1.z, a1.w};
            float bv[8] = {b0.x, b0.y, b0.z, b0.w, b1.x, b1.y, b1.z, b1.w};
            #pragma unroll
            for (int r = 0; r < 8; ++r)
                #pragma unroll
                for (int c = 0; c < 8; ++c)
                    acc[r][c] = fmaf(av[r], bv[c], acc[r][c]);
        }
        __syncthreads();
    }
    #pragma unroll
    for (int r = 0; r < 8; ++r) {
        int row = bm + m0 + r;
        if (row < N) {
            ushort4 o0 = {f2bf_rne(acc[r][0]), f2bf_rne(acc[r][1]),
                          f2bf_rne(acc[r][2]), f2bf_rne(acc[r][3])};
            ushort4 o1 = {f2bf_rne(acc[r][4]), f2bf_rne(acc[r][5]),
                          f2bf_rne(acc[r][6]), f2bf_rne(acc[r][7])};
            *(ushort4*)(Y + (size_t)row * 128 + c4)      = o0;
            *(ushort4*)(Y + (size_t)row * 128 + 64 + c4) = o1;
        }
    }
}

// ---- FUSED: agg (64 dst rows -> LDS fp32, +bias, ReLU) then
//      Ybf16[64,128] = sA @ W[128,128].  BM=64, 3 blocks/CU.
__global__ __launch_bounds__(256) void k_ag128(
        const ushort_t* __restrict__ XW, const int* __restrict__ rowptr,
        const int2* __restrict__ csr, const float* __restrict__ dinv,
        const float* __restrict__ bias, const float* __restrict__ W,
        ushort_t* __restrict__ Y, int n) {
    __shared__ float sA[64][130];   // row-major [m][k]; f2 writes 2-way = free
    __shared__ float sW[32][128];
    const int tid = threadIdx.x;
    const int lane = tid & 63;
    const int wv = __builtin_amdgcn_readfirstlane(tid >> 6);
    const int bm = blockIdx.x * 64;
    const uint_t* xw = (const uint_t*)XW;   // row stride 64 uints (256 B)
    // ---- phase A: aggregate; wave wv owns rows [wv*16, wv*16+16) ----
    #pragma unroll 1
    for (int mi = 0; mi < 16; ++mi) {
        const int m = wv * 16 + mi;
        const int d = bm + m;
        if (d >= n) break;              // rows monotone; all reach barrier
        float dv = dinv[d];
        float w0 = dv * dv;
        uint_t sq = xw[(size_t)d * 64 + lane];
        float2 a;
        a.x = w0 * bflo(sq);
        a.y = w0 * bfhi(sq);
        int j = rowptr[d], end = rowptr[d + 1];
        for (; j + 8 <= end; j += 8) {
            int2 p0 = csr[j + 0], p1 = csr[j + 1], p2 = csr[j + 2], p3 = csr[j + 3];
            int2 p4 = csr[j + 4], p5 = csr[j + 5], p6 = csr[j + 6], p7 = csr[j + 7];
            uint_t u0 = xw[(size_t)p0.x * 64 + lane];
            uint_t u1 = xw[(size_t)p1.x * 64 + lane];
            uint_t u2 = xw[(size_t)p2.x * 64 + lane];
            uint_t u3 = xw[(size_t)p3.x * 64 + lane];
            uint_t u4 = xw[(size_t)p4.x * 64 + lane];
            uint_t u5 = xw[(size_t)p5.x * 64 + lane];
            uint_t u6 = xw[(size_t)p6.x * 64 + lane];
            uint_t u7 = xw[(size_t)p7.x * 64 + lane];
            float w0e = __int_as_float(p0.y), w1e = __int_as_float(p1.y);
            float w2e = __int_as_float(p2.y), w3e = __int_as_float(p3.y);
            float w4e = __int_as_float(p4.y), w5e = __int_as_float(p5.y);
            float w6e = __int_as_float(p6.y), w7e = __int_as_float(p7.y);
            a.x = fmaf(w0e, bflo(u0), a.x); a.y = fmaf(w0e, bfhi(u0), a.y);
            a.x = fmaf(w1e, bflo(u1), a.x); a.y = fmaf(w1e, bfhi(u1), a.y);
            a.x = fmaf(w2e, bflo(u2), a.x); a.y = fmaf(w2e, bfhi(u2), a.y);
            a.x = fmaf(w3e, bflo(u3), a.x); a.y = fmaf(w3e, bfhi(u3), a.y);
            a.x = fmaf(w4e, bflo(u4), a.x); a.y = fmaf(w4e, bfhi(u4), a.y);
            a.x = fmaf(w5e, bflo(u5), a.x); a.y = fmaf(w5e, bfhi(u5), a.y);
            a.x = fmaf(w6e, bflo(u6), a.x); a.y = fmaf(w6e, bfhi(u6), a.y);
            a.x = fmaf(w7e, bflo(u7), a.x); a.y = fmaf(w7e, bfhi(u7), a.y);
        }
        for (; j < end; ++j) {
            int2 p = csr[j];
            float we = __int_as_float(p.y);
            uint_t u = xw[(size_t)p.x * 64 + lane];
            a.x = fmaf(we, bflo(u), a.x);
            a.y = fmaf(we, bfhi(u), a.y);
        }
        float2 b = ((const float2*)bias)[lane];
        a.x = fmaxf(a.x + b.x, 0.f);
        a.y = fmaxf(a.y + b.y, 0.f);
        *(float2*)(&sA[m][lane * 2]) = a;
    }
    __syncthreads();
    // ---- phase B: GEMM from LDS (identical numerics to old bufB path) ----
    const int m0 = (tid >> 4) * 4;
    const int c4 = (tid & 15) * 4;
    float acc[4][8] = {};
    for (int k0 = 0; k0 < 128; k0 += 32) {
        #pragma unroll
        for (int it = 0; it < 4; ++it) {
            int i = tid + it * 256;
            int wr = i >> 5;
            int wf = i & 31;
            *(float4*)(&sW[wr][wf * 4]) =
                *(const float4*)(W + (size_t)(k0 + wr) * 128 + wf * 4);
        }
        __syncthreads();
        #pragma unroll
        for (int kk = 0; kk < 32; ++kk) {
            float av[4];
            #pragma unroll
            for (int r = 0; r < 4; ++r) av[r] = sA[m0 + r][k0 + kk];
            float4 b0 = *(const float4*)(&sW[kk][c4]);
            float4 b1 = *(const float4*)(&sW[kk][64 + c4]);
            float bv[8] = {b0.x, b0.y, b0.z, b0.w, b1.x, b1.y, b1.z, b1.w};
            #pragma unroll
            for (int r = 0; r < 4; ++r)
                #pragma unroll
                for (int c = 0; c < 8; ++c)
                    acc[r][c] = fmaf(av[r], bv[c], acc[r][c]);
        }
        __syncthreads();
    }
    #pragma unroll
    for (int r = 0; r < 4; ++r) {
        int row = bm + m0 + r;
        if (row < n) {
            ushort4 o0 = {f2bf_rne(acc[r][0]), f2bf_rne(acc[r][1]),
                          f2bf_rne(acc[r][2]), f2bf_rne(acc[r][3])};
            ushort4 o1 = {f2bf_rne(acc[r][4]), f2bf_rne(acc[r][5]),
                          f2bf_rne(acc[r][6]), f2bf_rne(acc[r][7])};
            *(ushort4*)(Y + (size_t)row * 128 + c4)      = o0;
            *(ushort4*)(Y + (size_t)row * 128 + 64 + c4) = o1;
        }
    }
}

// ---- FUSED: agg (64 rows, +bias, ReLU) then Ybf16[64,40(str64)] = sA @ W[128,40].
__global__ __launch_bounds__(256) void k_ag40(
        const ushort_t* __restrict__ XW, const int* __restrict__ rowptr,
        const int2* __restrict__ csr, const float* __restrict__ dinv,
        const float* __restrict__ bias, const float* __restrict__ W,
        ushort_t* __restrict__ Y, int n) {
    __shared__ float sA[64][130];
    __shared__ float sW[32][40];
    const int tid = threadIdx.x;
    const int lane = tid & 63;
    const int wv = __builtin_amdgcn_readfirstlane(tid >> 6);
    const int bm = blockIdx.x * 64;
    const uint_t* xw = (const uint_t*)XW;
    #pragma unroll 1
    for (int mi = 0; mi < 16; ++mi) {
        const int m = wv * 16 + mi;
        const int d = bm + m;
        if (d >= n) break;
        float dv = dinv[d];
        float w0 = dv * dv;
        uint_t sq = xw[(size_t)d * 64 + lane];
        float2 a;
        a.x = w0 * bflo(sq);
        a.y = w0 * bfhi(sq);
        int j = rowptr[d], end = rowptr[d + 1];
        for (; j + 8 <= end; j += 8) {
            int2 p0 = csr[j + 0], p1 = csr[j + 1], p2 = csr[j + 2], p3 = csr[j + 3];
            int2 p4 = csr[j + 4], p5 = csr[j + 5], p6 = csr[j + 6], p7 = csr[j + 7];
            uint_t u0 = xw[(size_t)p0.x * 64 + lane];
            uint_t u1 = xw[(size_t)p1.x * 64 + lane];
            uint_t u2 = xw[(size_t)p2.x * 64 + lane];
            uint_t u3 = xw[(size_t)p3.x * 64 + lane];
            uint_t u4 = xw[(size_t)p4.x * 64 + lane];
            uint_t u5 = xw[(size_t)p5.x * 64 + lane];
            uint_t u6 = xw[(size_t)p6.x * 64 + lane];
            uint_t u7 = xw[(size_t)p7.x * 64 + lane];
            float w0e = __int_as_float(p0.y), w1e = __int_as_float(p1.y);
            float w2e = __int_as_float(p2.y), w3e = __int_as_float(p3.y);
            float w4e = __int_as_float(p4.y), w5e = __int_as_float(p5.y);
            float w6e = __int_as_float(p6.y), w7e = __int_as_float(p7.y);
            a.x = fmaf(w0e, bflo(u0), a.x); a.y = fmaf(w0e, bfhi(u0), a.y);
            a.x = fmaf(w1e, bflo(u1), a.x); a.y = fmaf(w1e, bfhi(u1), a.y);
            a.x = fmaf(w2e, bflo(u2), a.x); a.y = fmaf(w2e, bfhi(u2), a.y);
            a.x = fmaf(w3e, bflo(u3), a.x); a.y = fmaf(w3e, bfhi(u3), a.y);
            a.x = fmaf(w4e, bflo(u4), a.x); a.y = fmaf(w4e, bfhi(u4), a.y);
            a.x = fmaf(w5e, bflo(u5), a.x); a.y = fmaf(w5e, bfhi(u5), a.y);
            a.x = fmaf(w6e, bflo(u6), a.x); a.y = fmaf(w6e, bfhi(u6), a.y);
            a.x = fmaf(w7e, bflo(u7), a.x); a.y = fmaf(w7e, bfhi(u7), a.y);
        }
        for (; j < end; ++j) {
            int2 p = csr[j];
            float we = __int_as_float(p.y);
            uint_t u = xw[(size_t)p.x * 64 + lane];
            a.x = fmaf(we, bflo(u), a.x);
            a.y = fmaf(we, bfhi(u), a.y);
        }
        float2 b = ((const float2*)bias)[lane];
        a.x = fmaxf(a.x + b.x, 0.f);
        a.y = fmaxf(a.y + b.y, 0.f);
        *(float2*)(&sA[m][lane * 2]) = a;
    }
    __syncthreads();
    const int m0 = (tid >> 3) * 2;
    const int n0 = (tid & 7) * 5;
    float acc[2][5] = {};
    for (int k0 = 0; k0 < 128; k0 += 32) {
        for (int i = tid; i < 320; i += 256) {
            int wr = i / 10;
            int wf = i - wr * 10;
            *(float4*)(&sW[wr][wf * 4]) =
                *(const float4*)(W + (size_t)(k0 + wr) * 40 + wf * 4);
        }
        __syncthreads();
        #pragma unroll
        for (int kk = 0; kk < 32; ++kk) {
            float av0 = sA[m0][k0 + kk];
            float av1 = sA[m0 + 1][k0 + kk];
            #pragma unroll
            for (int c = 0; c < 5; ++c) {
                float b = sW[kk][n0 + c];
                acc[0][c] = fmaf(av0, b, acc[0][c]);
                acc[1][c] = fmaf(av1, b, acc[1][c]);
            }
        }
        __syncthreads();
    }
    #pragma unroll
    for (int r = 0; r < 2; ++r) {
        int row = bm + m0 + r;
        if (row < n) {
            #pragma unroll
            for (int c = 0; c < 5; ++c)
                Y[(size_t)row * 64 + n0 + c] = f2bf_rne(acc[r][c]);
        }
    }
}

// Half-wave per dst, F=40 bf16 rows padded to stride 64 (R14 form).
__global__ __launch_bounds__(256) void k_agg40(
        const ushort_t* __restrict__ XW, const int* __restrict__ rowptr,
        const int2* __restrict__ csr, const float* __restrict__ dinv,
        const float* __restrict__ bias, float* __restrict__ out, int n) {
    const int lane = threadIdx.x & 31;
    const int sub  = threadIdx.x >> 5;
    const int d = blockIdx.x * 8 + sub;
    if (d >= n || lane >= 20) return;
    const uint_t* xw = (const uint_t*)XW;       // row stride 32 uints
    float dv = dinv[d];
    float w0 = dv * dv;
    uint_t sq = xw[(size_t)d * 32 + lane];
    float2 a;
    a.x = w0 * bflo(sq);
    a.y = w0 * bfhi(sq);
    int j = rowptr[d], end = rowptr[d + 1];
    for (; j + 4 <= end; j += 4) {
        int2 p0 = csr[j + 0], p1 = csr[j + 1], p2 = csr[j + 2], p3 = csr[j + 3];
        uint_t u0 = xw[(size_t)p0.x * 32 + lane];
        uint_t u1 = xw[(size_t)p1.x * 32 + lane];
        uint_t u2 = xw[(size_t)p2.x * 32 + lane];
        uint_t u3 = xw[(size_t)p3.x * 32 + lane];
        float w0e = __int_as_float(p0.y), w1e = __int_as_float(p1.y);
        float w2e = __int_as_float(p2.y), w3e = __int_as_float(p3.y);
        a.x = fmaf(w0e, bflo(u0), a.x); a.y = fmaf(w0e, bfhi(u0), a.y);
        a.x = fmaf(w1e, bflo(u1), a.x); a.y = fmaf(w1e, bfhi(u1), a.y);
        a.x = fmaf(w2e, bflo(u2), a.x); a.y = fmaf(w2e, bfhi(u2), a.y);
        a.x = fmaf(w3e, bflo(u3), a.x); a.y = fmaf(w3e, bfhi(u3), a.y);
    }
    for (; j < end; ++j) {
        int2 p = csr[j];
        float we = __int_as_float(p.y);
        uint_t u = xw[(size_t)p.x * 32 + lane];
        a.x = fmaf(we, bflo(u), a.x);
        a.y = fmaf(we, bfhi(u), a.y);
    }
    float2 b = ((const float2*)bias)[lane];
    a.x += b.x; a.y += b.y;
    ((float2*)out)[(size_t)d * 20 + lane] = a;
}

static inline int cdiv(long long a, int b) { return (int)((a + b - 1) / b); }

extern "C" void kernel_launch(void* const* d_in, const int* in_sizes, int n_in,
                              void* d_out, int out_size, void* d_ws, size_t ws_size,
                              hipStream_t stream) {
    const float* x  = (const float*)d_in[0];
    const int*   ei = (const int*)d_in[1];
    const float* W1 = (const float*)d_in[2];
    const float* b1 = (const float*)d_in[3];
    const float* W2 = (const float*)d_in[4];
    const float* b2 = (const float*)d_in[5];
    const float* W3 = (const float*)d_in[6];
    const float* b3 = (const float*)d_in[7];
    float* out = (float*)d_out;

    const int N = in_sizes[0] / 128;   // 50000
    const int E = in_sizes[1] / 2;     // 800000
    const int nb = cdiv(N, 256);       // 196 scan blocks (co-resident)

    char* ws = (char*)d_ws;
    int*   deg    = (int*)ws;                 ws += (size_t)N * 4;
    unsigned long long* partials = (unsigned long long*)ws;
                                              ws += (size_t)nb * 8;
    int*   rowptr = (int*)ws;                 ws += (size_t)(N + 1) * 4;
    int*   cursor = (int*)ws;                 ws += (size_t)N * 4;
    float* dinv   = (float*)ws;               ws += (size_t)N * 4;
    ws = (char*)(((uintptr_t)ws + 127) & ~(uintptr_t)127);
    int2*     csr  = (int2*)ws;               ws += (size_t)E * 8;
    ushort_t* bufA = (ushort_t*)ws;           ws += (size_t)N * 128 * 2;
    ushort_t* bufC = (ushort_t*)ws;           ws += (size_t)N * 128 * 2;
    ushort_t* bufD = (ushort_t*)ws;

    const int BT = 256;
    const int gemmGrid = cdiv(N, 128);          // 391
    const int degGrid  = cdiv(E, BT);           // 3125

    // memset covers deg AND partials (contiguous).
    hipMemsetAsync(deg, 0, (size_t)N * 4 + (size_t)nb * 8, stream);

    // layer-1 GEMM ∪ degree count (independent work, one dispatch)
    k_l1<<<gemmGrid + degGrid, 256, 0, stream>>>(x, W1, bufA, N,
                                                 ei, deg, E, gemmGrid);
    // CSR build
    k_scan<<<nb, 256, 0, stream>>>(deg, partials, rowptr, cursor, dinv, N);
    k_fill<<<cdiv(E, BT) * 8, 256, 0, stream>>>(ei, cursor, dinv, csr, E, N);

    // fused agg1 + gemm2 ; fused agg2 + gemm3 ; final agg
    k_ag128<<<cdiv(N, 64), 256, 0, stream>>>(bufA, rowptr, csr, dinv, b1, W2, bufC, N);
    k_ag40 <<<cdiv(N, 64), 256, 0, stream>>>(bufC, rowptr, csr, dinv, b2, W3, bufD, N);
    k_agg40<<<cdiv(N, 8), 256, 0, stream>>>(bufD, rowptr, csr, dinv, b3, out, N);
}